// Round 1
// baseline (4431.266 us; speedup 1.0000x reference)
//
#include <hip/hip_runtime.h>

#define T_STEPS 256
#define ISZ 16
#define HID 40
#define G3 120  // 3*HID

__device__ __forceinline__ float sigm(float v) {
    return 1.0f / (1.0f + __expf(-v));
}
__device__ __forceinline__ float tanh_f(float v) {
    return 1.0f - 2.0f / (__expf(2.0f * v) + 1.0f);
}

// Block: 256 threads = 2 stripes x 128 lanes. Each stripe: 120 active lanes
// (one per gate-row), handles 8 batch elements. Grid: 256 blocks (16 elems each).
// Weights live in VGPRs (136/lane); h-state and x are shared via LDS broadcast.
__global__ __launch_bounds__(256, 2)
void gru2_kernel(const float* __restrict__ x,
                 const float* __restrict__ Wih0, const float* __restrict__ Whh0,
                 const float* __restrict__ bih0, const float* __restrict__ bhh0,
                 const float* __restrict__ Wih1, const float* __restrict__ Whh1,
                 const float* __restrict__ bih1, const float* __restrict__ bhh1,
                 float* __restrict__ out)
{
    __shared__ __align__(16) float Lx[16][ISZ];   // [e_local][k] staged x_t
    __shared__ __align__(16) float H0s[16][HID];  // [e_local][k] layer-0 h
    __shared__ __align__(16) float H1s[16][HID];  // layer-1 h
    __shared__ __align__(16) float Gr[HID][16];   // [unit][e_local] sigmoid(r)
    __shared__ __align__(16) float Gz[HID][16];   // sigmoid(z)
    __shared__ __align__(16) float Gnx[HID][16];  // n input-part (pre-activation)
    __shared__ __align__(16) float Gnh[HID][16];  // n hidden-part (pre-activation)

    const int tid    = threadIdx.x;
    const int stripe = tid >> 7;       // 0 or 1
    const int lane_s = tid & 127;      // lane within stripe
    const bool active = lane_s < G3;
    const int row  = active ? lane_s : 0;  // gate-row 0..119
    const int ebl  = stripe * 8;           // stripe's first elem within block
    const int e0   = blockIdx.x * 16;      // block's first global batch elem

    // ---- weights into registers (persist across the whole t-loop) ----
    float wi0[ISZ], wh0[HID], wi1[HID], wh1[HID];
    #pragma unroll
    for (int k = 0; k < ISZ; ++k) wi0[k] = Wih0[row * ISZ + k];
    #pragma unroll
    for (int k = 0; k < HID; ++k) wh0[k] = Whh0[row * HID + k];
    #pragma unroll
    for (int k = 0; k < HID; ++k) wi1[k] = Wih1[row * HID + k];
    #pragma unroll
    for (int k = 0; k < HID; ++k) wh1[k] = Whh1[row * HID + k];
    const float bx0 = bih0[row], bh0 = bhh0[row];
    const float bx1 = bih1[row], bh1 = bhh1[row];

    // init h states to zero
    for (int idx = tid; idx < 16 * HID; idx += 256) {
        ((float*)H0s)[idx] = 0.0f;
        ((float*)H1s)[idx] = 0.0f;
    }

    const int gate = row / HID;  // 0=r, 1=z, 2=n
    const int unit = row % HID;

    const float* xblk = x + (size_t)e0 * (T_STEPS * ISZ);

    for (int t = 0; t < T_STEPS; ++t) {
        // ---- stage x_t for the block's 16 elems ----
        {
            const int e_l = tid >> 4, k = tid & 15;
            Lx[e_l][k] = xblk[(size_t)e_l * (T_STEPS * ISZ) + t * ISZ + k];
        }
        __syncthreads();  // Lx ready; also orders prev-iter H1 assembly

        float ax[8], ah[8];
        // ---- layer-0 dot products (row x { x_t , h0 }) ----
        #pragma unroll
        for (int e = 0; e < 8; ++e) {
            const float4* xv = (const float4*)Lx[ebl + e];
            float s = bx0;
            #pragma unroll
            for (int k4 = 0; k4 < 4; ++k4) {
                float4 v = xv[k4];
                s += wi0[k4*4+0]*v.x + wi0[k4*4+1]*v.y + wi0[k4*4+2]*v.z + wi0[k4*4+3]*v.w;
            }
            ax[e] = s;
            const float4* hv = (const float4*)H0s[ebl + e];
            float h = bh0;
            #pragma unroll
            for (int k4 = 0; k4 < 10; ++k4) {
                float4 v = hv[k4];
                h += wh0[k4*4+0]*v.x + wh0[k4*4+1]*v.y + wh0[k4*4+2]*v.z + wh0[k4*4+3]*v.w;
            }
            ah[e] = h;
        }
        if (active) {
            if (gate == 0) {
                #pragma unroll
                for (int e = 0; e < 8; ++e) Gr[unit][ebl + e] = sigm(ax[e] + ah[e]);
            } else if (gate == 1) {
                #pragma unroll
                for (int e = 0; e < 8; ++e) Gz[unit][ebl + e] = sigm(ax[e] + ah[e]);
            } else {
                #pragma unroll
                for (int e = 0; e < 8; ++e) { Gnx[unit][ebl + e] = ax[e]; Gnh[unit][ebl + e] = ah[e]; }
            }
        }
        __syncthreads();

        // ---- layer-0 gate assembly: h0' = (1-z)*n + z*h0 ----
        for (int task = lane_s; task < 320; task += 128) {
            const int i  = task % HID;
            const int es = task / HID;       // 0..7 within stripe
            const int el = ebl + es;
            const float r  = Gr[i][el];
            const float z  = Gz[i][el];
            const float nx = Gnx[i][el];
            const float nh = Gnh[i][el];
            const float n  = tanh_f(nx + r * nh);
            const float ho = H0s[el][i];
            H0s[el][i] = (1.0f - z) * n + z * ho;
        }
        __syncthreads();

        // ---- layer-1 dot products (row x { h0' , h1 }) ----
        #pragma unroll
        for (int e = 0; e < 8; ++e) {
            const float4* xv = (const float4*)H0s[ebl + e];
            float s = bx1;
            #pragma unroll
            for (int k4 = 0; k4 < 10; ++k4) {
                float4 v = xv[k4];
                s += wi1[k4*4+0]*v.x + wi1[k4*4+1]*v.y + wi1[k4*4+2]*v.z + wi1[k4*4+3]*v.w;
            }
            ax[e] = s;
            const float4* hv = (const float4*)H1s[ebl + e];
            float h = bh1;
            #pragma unroll
            for (int k4 = 0; k4 < 10; ++k4) {
                float4 v = hv[k4];
                h += wh1[k4*4+0]*v.x + wh1[k4*4+1]*v.y + wh1[k4*4+2]*v.z + wh1[k4*4+3]*v.w;
            }
            ah[e] = h;
        }
        if (active) {
            if (gate == 0) {
                #pragma unroll
                for (int e = 0; e < 8; ++e) Gr[unit][ebl + e] = sigm(ax[e] + ah[e]);
            } else if (gate == 1) {
                #pragma unroll
                for (int e = 0; e < 8; ++e) Gz[unit][ebl + e] = sigm(ax[e] + ah[e]);
            } else {
                #pragma unroll
                for (int e = 0; e < 8; ++e) { Gnx[unit][ebl + e] = ax[e]; Gnh[unit][ebl + e] = ah[e]; }
            }
        }
        __syncthreads();

        // ---- layer-1 gate assembly: h1' = (1-z)*n + z*h1 ----
        for (int task = lane_s; task < 320; task += 128) {
            const int i  = task % HID;
            const int es = task / HID;
            const int el = ebl + es;
            const float r  = Gr[i][el];
            const float z  = Gz[i][el];
            const float nx = Gnx[i][el];
            const float nh = Gnh[i][el];
            const float n  = tanh_f(nx + r * nh);
            const float ho = H1s[el][i];
            H1s[el][i] = (1.0f - z) * n + z * ho;
        }
        // no sync here: next iteration's post-x-stage sync orders H1 updates
        // before their next readers (layer-1 dots of t+1).
    }

    __syncthreads();
    // ---- write final layer-1 hidden state: out[(e0+e)*40 + i] ----
    for (int idx = tid; idx < 16 * HID; idx += 256) {
        out[(size_t)e0 * HID + idx] = ((float*)H1s)[idx];
    }
}

extern "C" void kernel_launch(void* const* d_in, const int* in_sizes, int n_in,
                              void* d_out, int out_size, void* d_ws, size_t ws_size,
                              hipStream_t stream) {
    const float* x    = (const float*)d_in[0];
    const float* Wih0 = (const float*)d_in[1];
    const float* Whh0 = (const float*)d_in[2];
    const float* bih0 = (const float*)d_in[3];
    const float* bhh0 = (const float*)d_in[4];
    const float* Wih1 = (const float*)d_in[5];
    const float* Whh1 = (const float*)d_in[6];
    const float* bih1 = (const float*)d_in[7];
    const float* bhh1 = (const float*)d_in[8];
    float* out = (float*)d_out;

    dim3 grid(256), block(256);
    hipLaunchKernelGGL(gru2_kernel, grid, block, 0, stream,
                       x, Wih0, Whh0, bih0, bhh0, Wih1, Whh1, bih1, bhh1, out);
}

// Round 2
// 1950.410 us; speedup vs baseline: 2.2720x; 2.2720x over previous
//
#include <hip/hip_runtime.h>

#define T_STEPS 256
#define ISZ 16
#define HID 40
#define G3 120  // 3*HID

__device__ __forceinline__ float sigm(float v) {
    return 1.0f / (1.0f + __expf(-v));
}
__device__ __forceinline__ float tanh_f(float v) {
    return 1.0f - 2.0f / (__expf(2.0f * v) + 1.0f);
}

// Block: 256 threads = 2 stripes x 128 lanes. Each stripe: 120 active lanes
// (one per gate-row), handles 8 batch elements. Grid: 256 blocks (16 elems each).
// Weights live in VGPRs (136/lane, needs launch_bounds(256,1) -> 512 VGPR
// budget; (256,2) made the compiler cap at 128 and spill 9 GB to scratch).
// h-state / x reads are wave-uniform LDS broadcasts; gate buffers are
// [elem][unit] so unit-stride = 1 float -> no bank conflicts.
__global__ __launch_bounds__(256, 1)
void gru2_kernel(const float* __restrict__ x,
                 const float* __restrict__ Wih0, const float* __restrict__ Whh0,
                 const float* __restrict__ bih0, const float* __restrict__ bhh0,
                 const float* __restrict__ Wih1, const float* __restrict__ Whh1,
                 const float* __restrict__ bih1, const float* __restrict__ bhh1,
                 float* __restrict__ out)
{
    __shared__ __align__(16) float Lx[16][ISZ];      // [e_local][k] staged x_t
    __shared__ __align__(16) float H0s[16][HID];     // [e_local][unit] layer-0 h
    __shared__ __align__(16) float H1s[16][HID];     // layer-1 h
    __shared__ __align__(16) float G[4][16][HID];    // 0:pre_r 1:pre_z 2:nx 3:nh

    const int tid    = threadIdx.x;
    const int stripe = tid >> 7;       // 0 or 1
    const int lane_s = tid & 127;      // lane within stripe
    const bool active = lane_s < G3;
    const int row  = active ? lane_s : 0;  // gate-row 0..119
    const int ebl  = stripe * 8;           // stripe's first elem within block
    const int e0   = blockIdx.x * 16;      // block's first global batch elem

    // ---- weights into registers (persist across the whole t-loop) ----
    float wi0[ISZ], wh0[HID], wi1[HID], wh1[HID];
    #pragma unroll
    for (int k = 0; k < ISZ; ++k) wi0[k] = Wih0[row * ISZ + k];
    #pragma unroll
    for (int k = 0; k < HID; ++k) wh0[k] = Whh0[row * HID + k];
    #pragma unroll
    for (int k = 0; k < HID; ++k) wi1[k] = Wih1[row * HID + k];
    #pragma unroll
    for (int k = 0; k < HID; ++k) wh1[k] = Whh1[row * HID + k];
    const float bx0 = bih0[row], bh0 = bhh0[row];
    const float bx1 = bih1[row], bh1 = bhh1[row];

    // init h states to zero
    for (int idx = tid; idx < 16 * HID; idx += 256) {
        ((float*)H0s)[idx] = 0.0f;
        ((float*)H1s)[idx] = 0.0f;
    }

    const int gate = row / HID;  // 0=r, 1=z, 2=n
    const int unit = row % HID;
    const bool is_n = (gate == 2);

    const float* xblk = x + (size_t)e0 * (T_STEPS * ISZ);

    for (int t = 0; t < T_STEPS; ++t) {
        // ---- stage x_t for the block's 16 elems ----
        {
            const int e_l = tid >> 4, k = tid & 15;
            Lx[e_l][k] = xblk[(size_t)e_l * (T_STEPS * ISZ) + t * ISZ + k];
        }
        __syncthreads();  // Lx ready; also orders prev-iter H1 assembly

        float ax[8], ah[8];
        // ---- layer-0 dot products (row x { x_t , h0 }) ----
        #pragma unroll
        for (int e = 0; e < 8; ++e) {
            const float4* xv = (const float4*)Lx[ebl + e];
            float s = bx0;
            #pragma unroll
            for (int k4 = 0; k4 < 4; ++k4) {
                float4 v = xv[k4];
                s += wi0[k4*4+0]*v.x + wi0[k4*4+1]*v.y + wi0[k4*4+2]*v.z + wi0[k4*4+3]*v.w;
            }
            ax[e] = s;
            const float4* hv = (const float4*)H0s[ebl + e];
            float h = bh0;
            #pragma unroll
            for (int k4 = 0; k4 < 10; ++k4) {
                float4 v = hv[k4];
                h += wh0[k4*4+0]*v.x + wh0[k4*4+1]*v.y + wh0[k4*4+2]*v.z + wh0[k4*4+3]*v.w;
            }
            ah[e] = h;
        }
        if (active) {
            // r/z rows store pre-activation sum; n rows store (nx, nh) split.
            #pragma unroll
            for (int e = 0; e < 8; ++e) {
                G[gate][ebl + e][unit] = is_n ? ax[e] : (ax[e] + ah[e]);
            }
            if (is_n) {
                #pragma unroll
                for (int e = 0; e < 8; ++e) G[3][ebl + e][unit] = ah[e];
            }
        }
        __syncthreads();

        // ---- layer-0 gate assembly: h0' = (1-z)*n + z*h0 ----
        for (int task = lane_s; task < 320; task += 128) {
            const int i  = task % HID;
            const int el = ebl + task / HID;
            const float r  = sigm(G[0][el][i]);
            const float z  = sigm(G[1][el][i]);
            const float n  = tanh_f(G[2][el][i] + r * G[3][el][i]);
            H0s[el][i] = (1.0f - z) * n + z * H0s[el][i];
        }
        __syncthreads();

        // ---- layer-1 dot products (row x { h0' , h1 }) ----
        #pragma unroll
        for (int e = 0; e < 8; ++e) {
            const float4* xv = (const float4*)H0s[ebl + e];
            float s = bx1;
            #pragma unroll
            for (int k4 = 0; k4 < 10; ++k4) {
                float4 v = xv[k4];
                s += wi1[k4*4+0]*v.x + wi1[k4*4+1]*v.y + wi1[k4*4+2]*v.z + wi1[k4*4+3]*v.w;
            }
            ax[e] = s;
            const float4* hv = (const float4*)H1s[ebl + e];
            float h = bh1;
            #pragma unroll
            for (int k4 = 0; k4 < 10; ++k4) {
                float4 v = hv[k4];
                h += wh1[k4*4+0]*v.x + wh1[k4*4+1]*v.y + wh1[k4*4+2]*v.z + wh1[k4*4+3]*v.w;
            }
            ah[e] = h;
        }
        if (active) {
            #pragma unroll
            for (int e = 0; e < 8; ++e) {
                G[gate][ebl + e][unit] = is_n ? ax[e] : (ax[e] + ah[e]);
            }
            if (is_n) {
                #pragma unroll
                for (int e = 0; e < 8; ++e) G[3][ebl + e][unit] = ah[e];
            }
        }
        __syncthreads();

        // ---- layer-1 gate assembly: h1' = (1-z)*n + z*h1 ----
        for (int task = lane_s; task < 320; task += 128) {
            const int i  = task % HID;
            const int el = ebl + task / HID;
            const float r  = sigm(G[0][el][i]);
            const float z  = sigm(G[1][el][i]);
            const float n  = tanh_f(G[2][el][i] + r * G[3][el][i]);
            H1s[el][i] = (1.0f - z) * n + z * H1s[el][i];
        }
        // no sync here: next iteration's post-x-stage sync orders H1 updates
        // before their next readers (layer-1 dots of t+1).
    }

    __syncthreads();
    // ---- write final layer-1 hidden state: out[(e0+e)*40 + i] ----
    for (int idx = tid; idx < 16 * HID; idx += 256) {
        out[(size_t)e0 * HID + idx] = ((float*)H1s)[idx];
    }
}

extern "C" void kernel_launch(void* const* d_in, const int* in_sizes, int n_in,
                              void* d_out, int out_size, void* d_ws, size_t ws_size,
                              hipStream_t stream) {
    const float* x    = (const float*)d_in[0];
    const float* Wih0 = (const float*)d_in[1];
    const float* Whh0 = (const float*)d_in[2];
    const float* bih0 = (const float*)d_in[3];
    const float* bhh0 = (const float*)d_in[4];
    const float* Wih1 = (const float*)d_in[5];
    const float* Whh1 = (const float*)d_in[6];
    const float* bih1 = (const float*)d_in[7];
    const float* bhh1 = (const float*)d_in[8];
    float* out = (float*)d_out;

    dim3 grid(256), block(256);
    hipLaunchKernelGGL(gru2_kernel, grid, block, 0, stream,
                       x, Wih0, Whh0, bih0, bhh0, Wih1, Whh1, bih1, bhh1, out);
}